// Round 6
// baseline (236.708 us; speedup 1.0000x reference)
//
#include <hip/hip_runtime.h>
#include <hip/hip_bf16.h>

// LightGCN layer: out = adj @ (x * (u >= 0.1) / 0.9)
// x: [16384,64] f32, adj: [16384,16384] f32, u: [16384,64] f32, out: [16384,64] f32
//
// Round 6: r5's barrier-free 2-deep register pipeline, with
//  (a) 2 waves/block in-block K-split -> 8 waves/CU; independent streams fill
//      each other's issue gaps (r5 had 4 waves/CU and sawtoothed demand);
//      single end-of-kernel LDS reduce + one __syncthreads.
//  (b) non-temporal adj loads (zero-reuse stream; stop evicting the shared
//      2 MB B buffer from each XCD L2) and non-temporal C stores.
// Everything else (layouts, counted-vmcnt ordering, B-in-regs) unchanged from r5.

#define NN 16384
#define DD 64
#define MT 16
#define KP 64                  // K floats per phase
#define NPHW 128               // phases per wave (K/2 each)
#define CHUNK 2560             // staged A bytes per phase (16 rows x 64 k bf16, padded)

typedef __attribute__((ext_vector_type(4))) float floatx4;
typedef __attribute__((ext_vector_type(4))) short short4v;
typedef __attribute__((ext_vector_type(8))) short short8;

static __device__ __forceinline__ short bf16b(float f) {
    union { __hip_bfloat16 h; short s; } cv;
    cv.h = __float2bfloat16(f);
    return cv.s;
}

// B in MFMA fragment-linear order (unchanged, verified r1-r5):
// chunk c = s*256 + f*64 + lane; shorts at c*8:
// element j = B[s*32 + (lane>>4)*8 + j][f*16 + (lane&15)]
__global__ void __launch_bounds__(256) prep_kernel(const float* __restrict__ x,
                                                   const float* __restrict__ u,
                                                   short* __restrict__ bfrag) {
    int c = blockIdx.x * 256 + threadIdx.x;
    int lane = c & 63;
    int f = (c >> 6) & 3;
    int s = c >> 8;
    int col = f * 16 + (lane & 15);
    int k0 = s * 32 + (lane >> 4) * 8;
    short8 v;
#pragma unroll
    for (int j = 0; j < 8; ++j) {
        int idx = (k0 + j) * DD + col;
        float xv = x[idx];
        float uv = u[idx];
        float xd = (uv >= 0.1f) ? xv * (1.0f / 0.9f) : 0.0f;
        v[j] = bf16b(xd);
    }
    *reinterpret_cast<short8*>(bfrag + (size_t)c * 8) = v;
}

__global__ void __launch_bounds__(128, 2) gemm_kernel(const float* __restrict__ adj,
                                                      const short* __restrict__ bfrag,
                                                      float* __restrict__ out) {
    __shared__ char smem[2 * 2 * CHUNK];     // per-wave private dbuf (2 waves)
    __shared__ float red[16 * 64];           // K-split reduction buffer

    const int lane = threadIdx.x & 63;
    const int w    = threadIdx.x >> 6;       // 0/1: K-half
    const int r    = lane & 15;              // MFMA A-row / output col
    const int kg   = lane >> 4;              // MFMA k-group
    const int row0 = blockIdx.x * MT;

    char* c0 = smem + w * 2 * CHUNK;
    char* c1 = c0 + CHUNK;

    // A-load addressing: instr g covers rows {4g+lrow}; 16 lanes x 16B = 256B/row
    const int lrow = lane >> 4;              // 0..3
    const int lm   = lane & 15;              // 16B slot within the 256B row-run
    // STASH: lane holds (row = 4g+lrow, k = lm*4..+3); layout byte =
    //   s*1280 + r*80 + kg*16 + half*8   (conflict-free b128 read, r5-verified)
    const int sbyte = (lm >> 3) * 1280 + lrow * 80 + (((lm & 7) >> 1) * 16) + (lm & 1) * 8;
    const int aoff  = r * 80 + kg * 16;      // A-frag read offset (+ s*1280)

    const float* apA = adj + (size_t)(row0 + lrow) * NN + w * (NN / 2) + lm * 4;
    const float* apB = apA + KP;
    const short* bpA = bfrag + (size_t)w * NPHW * 4096 + (size_t)lane * 8;
    const short* bpB = bpA + 4096;

    floatx4 Aa[4], Ab[4];
    short8  Ba[8], Bb[8];

#define ISSUE_A(RA, AP)                                                        \
    {                                                                          \
        _Pragma("unroll")                                                      \
        for (int g = 0; g < 4; ++g)                                            \
            RA[g] = __builtin_nontemporal_load(                                \
                reinterpret_cast<const floatx4*>(AP + (size_t)g * 4 * NN));    \
        AP += 2 * KP;                                                          \
        asm volatile("" ::: "memory");                                         \
    }

#define ISSUE_B(RB, BP)                                                       \
    {                                                                         \
        _Pragma("unroll")                                                     \
        for (int s = 0; s < 2; ++s)                                           \
            _Pragma("unroll")                                                 \
            for (int f = 0; f < 4; ++f)                                       \
                RB[s * 4 + f] =                                               \
                    *reinterpret_cast<const short8*>(BP + s * 2048 + f * 512);\
        BP += 8192;                                                           \
        asm volatile("" ::: "memory");                                        \
    }

#define STASH(RA, C)                                                         \
    {                                                                        \
        _Pragma("unroll")                                                    \
        for (int g = 0; g < 4; ++g) {                                        \
            short4v w_;                                                      \
            w_.x = bf16b(RA[g].x); w_.y = bf16b(RA[g].y);                    \
            w_.z = bf16b(RA[g].z); w_.w = bf16b(RA[g].w);                    \
            *reinterpret_cast<short4v*>((C) + sbyte + g * 320) = w_;         \
        }                                                                    \
    }

    floatx4 acc0 = {0.f, 0.f, 0.f, 0.f};
    floatx4 acc1 = {0.f, 0.f, 0.f, 0.f};
    floatx4 acc2 = {0.f, 0.f, 0.f, 0.f};
    floatx4 acc3 = {0.f, 0.f, 0.f, 0.f};

#define COMPUTE(C, RB)                                                            \
    {                                                                             \
        _Pragma("unroll")                                                         \
        for (int s = 0; s < 2; ++s) {                                             \
            short8 af = *reinterpret_cast<const short8*>((C) + aoff + s * 1280);  \
            acc0 = __builtin_amdgcn_mfma_f32_16x16x32_bf16(af, RB[s*4+0], acc0, 0, 0, 0); \
            acc1 = __builtin_amdgcn_mfma_f32_16x16x32_bf16(af, RB[s*4+1], acc1, 0, 0, 0); \
            acc2 = __builtin_amdgcn_mfma_f32_16x16x32_bf16(af, RB[s*4+2], acc2, 0, 0, 0); \
            acc3 = __builtin_amdgcn_mfma_f32_16x16x32_bf16(af, RB[s*4+3], acc3, 0, 0, 0); \
        }                                                                         \
    }

    // prologue
    ISSUE_A(Aa, apA); ISSUE_B(Ba, bpA);   // wave-phase 0 -> set a
    ISSUE_A(Ab, apB); ISSUE_B(Bb, bpB);   // wave-phase 1 -> set b
    STASH(Aa, c0);                        // waits only set-a A loads (counted)

    for (int t = 0; t < NPHW; t += 2) {
        COMPUTE(c0, Ba);                                     // phase t
        if (t + 2 < NPHW) { ISSUE_A(Aa, apA); ISSUE_B(Ba, bpA); }
        STASH(Ab, c1);                                       // A(t+1) -> c1
        COMPUTE(c1, Bb);                                     // phase t+1
        if (t + 3 < NPHW) { ISSUE_A(Ab, apB); ISSUE_B(Bb, bpB); }
        if (t + 2 < NPHW) STASH(Aa, c0);                     // A(t+2) -> c0
    }

    // K-split reduce: wave 1 -> LDS, wave 0 adds and stores.
    // red layout [(f*4+j)*64 + lane]: 2 lanes/bank on every access (free).
    if (w == 1) {
#pragma unroll
        for (int j = 0; j < 4; ++j) {
            red[(0 * 4 + j) * 64 + lane] = acc0[j];
            red[(1 * 4 + j) * 64 + lane] = acc1[j];
            red[(2 * 4 + j) * 64 + lane] = acc2[j];
            red[(3 * 4 + j) * 64 + lane] = acc3[j];
        }
    }
    __syncthreads();
    if (w == 0) {
        // C/D: col(N) = r, row(M) = kg*4 + j  (verified r1-r5)
        const int orow = row0 + kg * 4;
        float* op = out + (size_t)orow * DD + r;
#pragma unroll
        for (int j = 0; j < 4; ++j) {
            __builtin_nontemporal_store(acc0[j] + red[(0 * 4 + j) * 64 + lane], op + (size_t)j * DD + 0);
            __builtin_nontemporal_store(acc1[j] + red[(1 * 4 + j) * 64 + lane], op + (size_t)j * DD + 16);
            __builtin_nontemporal_store(acc2[j] + red[(2 * 4 + j) * 64 + lane], op + (size_t)j * DD + 32);
            __builtin_nontemporal_store(acc3[j] + red[(3 * 4 + j) * 64 + lane], op + (size_t)j * DD + 48);
        }
    }
}

extern "C" void kernel_launch(void* const* d_in, const int* in_sizes, int n_in,
                              void* d_out, int out_size, void* d_ws, size_t ws_size,
                              hipStream_t stream) {
    const float* x   = (const float*)d_in[0];
    const float* adj = (const float*)d_in[1];
    const float* u   = (const float*)d_in[2];
    float* out = (float*)d_out;
    short* bfrag = (short*)d_ws;   // 16384*64 bf16 = 2 MB

    prep_kernel<<<dim3(512), dim3(256), 0, stream>>>(x, u, bfrag);
    gemm_kernel<<<dim3(NN / MT), dim3(128), 0, stream>>>(adj, bfrag, out);
}

// Round 7
// 232.158 us; speedup vs baseline: 1.0196x; 1.0196x over previous
//
#include <hip/hip_runtime.h>
#include <hip/hip_bf16.h>

// LightGCN layer: out = adj @ (x * (u >= 0.1) / 0.9)
// x: [16384,64] f32, adj: [16384,16384] f32, u: [16384,64] f32, out: [16384,64] f32
//
// Round 7: r5 (best, 219.7us) + ONE change: pipeline depth 2 -> 3.
//  - Three reg sets (a,b,c) + three wave-private LDS chunks. Every STASH/COMPUTE
//    vmcnt wait now leaves TWO full phase-sets (24 loads) outstanding instead of
//    one -> per-CU A-in-flight floor doubles -> DRAM never starves.
//  - r6's nt hints and in-block K-split reverted (regressed; bundled changes).
//  - Everything else byte-identical to r5: barrier-free single-wave blocks,
//    counted-vmcnt ordering only, B prefetched into regs AS MFMA fragments,
//    A LDS layout s*1280 + r*80 + kg*16 + half*8 (conflict-free b128 reads).

#define NN 16384
#define DD 64
#define MT 16
#define KP 64                  // K floats per phase
#define NPH (NN / KP)          // 256 phases
#define CHUNK 2560             // staged A bytes per phase (2 K-steps x 1280)

typedef __attribute__((ext_vector_type(4))) float floatx4;
typedef __attribute__((ext_vector_type(4))) short short4v;
typedef __attribute__((ext_vector_type(8))) short short8;

static __device__ __forceinline__ short bf16b(float f) {
    union { __hip_bfloat16 h; short s; } cv;
    cv.h = __float2bfloat16(f);
    return cv.s;
}

// B in MFMA fragment-linear order (unchanged, verified r1-r6):
// chunk c = s*256 + f*64 + lane; shorts at c*8:
// element j = B[s*32 + (lane>>4)*8 + j][f*16 + (lane&15)]
__global__ void __launch_bounds__(256) prep_kernel(const float* __restrict__ x,
                                                   const float* __restrict__ u,
                                                   short* __restrict__ bfrag) {
    int c = blockIdx.x * 256 + threadIdx.x;
    int lane = c & 63;
    int f = (c >> 6) & 3;
    int s = c >> 8;
    int col = f * 16 + (lane & 15);
    int k0 = s * 32 + (lane >> 4) * 8;
    short8 v;
#pragma unroll
    for (int j = 0; j < 8; ++j) {
        int idx = (k0 + j) * DD + col;
        float xv = x[idx];
        float uv = u[idx];
        float xd = (uv >= 0.1f) ? xv * (1.0f / 0.9f) : 0.0f;
        v[j] = bf16b(xd);
    }
    *reinterpret_cast<short8*>(bfrag + (size_t)c * 8) = v;
}

__global__ void __launch_bounds__(64) gemm_kernel(const float* __restrict__ adj,
                                                  const short* __restrict__ bfrag,
                                                  float* __restrict__ out) {
    __shared__ char smem[3 * CHUNK];   // 7680 B, wave-private (1 wave/block)
    char* c0 = smem;
    char* c1 = smem + CHUNK;
    char* c2 = smem + 2 * CHUNK;

    const int lane = threadIdx.x & 63;
    const int r    = lane & 15;        // MFMA A-row / output col
    const int kg   = lane >> 4;        // MFMA k-group
    const int row0 = blockIdx.x * MT;

    // A-load addressing: instr g covers rows {4g..4g+3}; 16 lanes x 16B = 256B/row
    const int lrow = lane >> 4;        // 0..3
    const int lm   = lane & 15;        // 16B slot within the 256B row-run
    // STASH: lane holds (row = 4g+lrow, k = lm*4..+3); layout byte =
    //   s*1280 + r*80 + kg*16 + half*8
    const int sbyte = (lm >> 3) * 1280 + lrow * 80 + (((lm & 7) >> 1) * 16) + (lm & 1) * 8;
    const int aoff  = r * 80 + kg * 16;   // A-frag read offset (+ s*1280)

    const float* apA = adj + (size_t)(row0 + lrow) * NN + lm * 4;   // phase 0
    const float* apB = apA + KP;                                    // phase 1
    const float* apC = apA + 2 * KP;                                // phase 2
    const short* bpA = bfrag + (size_t)lane * 8;                    // phase 0
    const short* bpB = bpA + 4096;                                  // phase 1
    const short* bpC = bpA + 8192;                                  // phase 2

    floatx4 Aa[4], Ab[4], Ac[4];
    short8  Ba[8], Bb[8], Bc[8];

#define ISSUE_A(RA, AP)                                                        \
    {                                                                          \
        _Pragma("unroll")                                                      \
        for (int g = 0; g < 4; ++g)                                            \
            RA[g] = *reinterpret_cast<const floatx4*>(AP + (size_t)g * 4 * NN);\
        AP += 3 * KP;                                                          \
        asm volatile("" ::: "memory");                                         \
    }

#define ISSUE_B(RB, BP)                                                       \
    {                                                                         \
        _Pragma("unroll")                                                     \
        for (int s = 0; s < 2; ++s)                                           \
            _Pragma("unroll")                                                 \
            for (int f = 0; f < 4; ++f)                                       \
                RB[s * 4 + f] =                                               \
                    *reinterpret_cast<const short8*>(BP + s * 2048 + f * 512);\
        BP += 12288;                                                          \
        asm volatile("" ::: "memory");                                        \
    }

#define STASH(RA, C)                                                         \
    {                                                                        \
        _Pragma("unroll")                                                    \
        for (int g = 0; g < 4; ++g) {                                        \
            short4v w_;                                                      \
            w_.x = bf16b(RA[g].x); w_.y = bf16b(RA[g].y);                    \
            w_.z = bf16b(RA[g].z); w_.w = bf16b(RA[g].w);                    \
            *reinterpret_cast<short4v*>((C) + sbyte + g * 320) = w_;         \
        }                                                                    \
    }

    floatx4 acc0 = {0.f, 0.f, 0.f, 0.f};
    floatx4 acc1 = {0.f, 0.f, 0.f, 0.f};
    floatx4 acc2 = {0.f, 0.f, 0.f, 0.f};
    floatx4 acc3 = {0.f, 0.f, 0.f, 0.f};

#define COMPUTE(C, RB)                                                            \
    {                                                                             \
        _Pragma("unroll")                                                         \
        for (int s = 0; s < 2; ++s) {                                             \
            short8 af = *reinterpret_cast<const short8*>((C) + aoff + s * 1280);  \
            acc0 = __builtin_amdgcn_mfma_f32_16x16x32_bf16(af, RB[s*4+0], acc0, 0, 0, 0); \
            acc1 = __builtin_amdgcn_mfma_f32_16x16x32_bf16(af, RB[s*4+1], acc1, 0, 0, 0); \
            acc2 = __builtin_amdgcn_mfma_f32_16x16x32_bf16(af, RB[s*4+2], acc2, 0, 0, 0); \
            acc3 = __builtin_amdgcn_mfma_f32_16x16x32_bf16(af, RB[s*4+3], acc3, 0, 0, 0); \
        }                                                                         \
    }

    // prologue: phases 0,1,2 in flight; stash phase 0
    ISSUE_A(Aa, apA); ISSUE_B(Ba, bpA);
    ISSUE_A(Ab, apB); ISSUE_B(Bb, bpB);
    ISSUE_A(Ac, apC); ISSUE_B(Bc, bpC);
    STASH(Aa, c0);    // waits only set-a A loads; sets b,c stay outstanding

    for (int t = 0; t < NPH; t += 3) {
        COMPUTE(c0, Ba);                                      // phase t
        if (t + 3 < NPH) { ISSUE_A(Aa, apA); ISSUE_B(Ba, bpA); }   // phase t+3
        if (t + 1 < NPH) {
            STASH(Ab, c1);                                    // phase t+1
            COMPUTE(c1, Bb);
        }
        if (t + 4 < NPH) { ISSUE_A(Ab, apB); ISSUE_B(Bb, bpB); }   // phase t+4
        if (t + 2 < NPH) {
            STASH(Ac, c2);                                    // phase t+2
            COMPUTE(c2, Bc);
        }
        if (t + 5 < NPH) { ISSUE_A(Ac, apC); ISSUE_B(Bc, bpC); }   // phase t+5
        if (t + 3 < NPH) STASH(Aa, c0);                       // phase t+3
    }

    // C/D: col(N) = r, row(M) = kg*4 + j  (verified r1-r6)
    const int orow = row0 + kg * 4;
    float* op = out + (size_t)orow * DD + r;
#pragma unroll
    for (int j = 0; j < 4; ++j) {
        op[(size_t)j * DD + 0]  = acc0[j];
        op[(size_t)j * DD + 16] = acc1[j];
        op[(size_t)j * DD + 32] = acc2[j];
        op[(size_t)j * DD + 48] = acc3[j];
    }
}

extern "C" void kernel_launch(void* const* d_in, const int* in_sizes, int n_in,
                              void* d_out, int out_size, void* d_ws, size_t ws_size,
                              hipStream_t stream) {
    const float* x   = (const float*)d_in[0];
    const float* adj = (const float*)d_in[1];
    const float* u   = (const float*)d_in[2];
    float* out = (float*)d_out;
    short* bfrag = (short*)d_ws;   // 16384*64 bf16 = 2 MB

    prep_kernel<<<dim3(512), dim3(256), 0, stream>>>(x, u, bfrag);
    gemm_kernel<<<dim3(NN / MT), dim3(64), 0, stream>>>(adj, bfrag, out);
}

// Round 8
// 210.847 us; speedup vs baseline: 1.1227x; 1.1011x over previous
//
#include <hip/hip_runtime.h>
#include <hip/hip_bf16.h>

// LightGCN layer: out = adj @ (x * (u >= 0.1) / 0.9)
// x: [16384,64] f32, adj: [16384,16384] f32, u: [16384,64] f32, out: [16384,64] f32
//
// Round 8: r5 (best, 219.7us) + ONE change: A-loads are 1KB-contiguous per
// instruction (one full row segment, 64 lanes x 16B), A-phase coarsened to 256
// floats. To keep A continuously in flight despite in-order vmcnt (B-waits drain
// older A issues), A(T+2) is issued in 4-row GROUPS, one group per 64-k
// sub-phase, interleaved with the B prefetch rhythm. Each group is ~3 sub-phases
// (~2.4us) old before any newer-B wait covers it -> drained only after arrival.
//  - Barrier-free single-wave blocks (1024 x 64), counted-vmcnt ordering only.
//  - B (frag-linear bf16 in d_ws, L2-resident) prefetched depth-2 into regs AS
//    MFMA fragments (r1-verified mapping). Unchanged from r5.
//  - A LDS sub-chunk layout s*1280 + r*80 + kg*16 + half*8 (r5-verified
//    conflict-free ds_read_b128); sub-chunks at u*2560; 2 chunks x 10240 B.

#define NN 16384
#define DD 64
#define MT 16
#define APH 256                // A-phase: K floats per staged chunk
#define NAPH (NN / APH)        // 64 A-phases
#define CHUNK 10240            // 4 sub-chunks x 2560 B

typedef __attribute__((ext_vector_type(4))) float floatx4;
typedef __attribute__((ext_vector_type(4))) short short4v;
typedef __attribute__((ext_vector_type(8))) short short8;

static __device__ __forceinline__ short bf16b(float f) {
    union { __hip_bfloat16 h; short s; } cv;
    cv.h = __float2bfloat16(f);
    return cv.s;
}

// B in MFMA fragment-linear order (unchanged, verified r1-r7):
// chunk c = s*256 + f*64 + lane; shorts at c*8:
// element j = B[s*32 + (lane>>4)*8 + j][f*16 + (lane&15)]
__global__ void __launch_bounds__(256) prep_kernel(const float* __restrict__ x,
                                                   const float* __restrict__ u,
                                                   short* __restrict__ bfrag) {
    int c = blockIdx.x * 256 + threadIdx.x;
    int lane = c & 63;
    int f = (c >> 6) & 3;
    int s = c >> 8;
    int col = f * 16 + (lane & 15);
    int k0 = s * 32 + (lane >> 4) * 8;
    short8 v;
#pragma unroll
    for (int j = 0; j < 8; ++j) {
        int idx = (k0 + j) * DD + col;
        float xv = x[idx];
        float uv = u[idx];
        float xd = (uv >= 0.1f) ? xv * (1.0f / 0.9f) : 0.0f;
        v[j] = bf16b(xd);
    }
    *reinterpret_cast<short8*>(bfrag + (size_t)c * 8) = v;
}

__global__ void __launch_bounds__(64) gemm_kernel(const float* __restrict__ adj,
                                                  const short* __restrict__ bfrag,
                                                  float* __restrict__ out) {
    __shared__ char smem[2 * CHUNK];   // 20480 B, wave-private (1 wave/block)
    char* c0 = smem;
    char* c1 = smem + CHUNK;

    const int lane = threadIdx.x & 63;
    const int r    = lane & 15;        // MFMA A-row / output col
    const int kg   = lane >> 4;        // MFMA k-group
    const int row0 = blockIdx.x * MT;

    // A-load: instr g loads row g's [T*256 + lane*4 .. +3] -> 1KB contiguous/instr
    const float* abase = adj + (size_t)row0 * NN + (size_t)lane * 4;
    // STASH: lane's 4 floats are k0 = lane*4 of row g. Decompose k0:
    //   u=lane>>4 (sub-chunk), s=(lane&15)>>3, kg'=(lane&7)>>1, half=lane&1
    const int sbyte = (lane >> 4) * 2560 + ((lane & 15) >> 3) * 1280 +
                      ((lane & 7) >> 1) * 16 + (lane & 1) * 8;
    const int aoff  = r * 80 + kg * 16;   // A-frag read (+ u*2560 + s*1280)

    const short* bpA = bfrag + (size_t)lane * 8;   // even sub-phases
    const short* bpB = bpA + 4096;                 // odd sub-phases

    floatx4 Sa[16], Sb[16];
    short8  Ba[8], Bb[8];

#define ISSUE_A4(RA, TT, U)                                                    \
    {                                                                          \
        _Pragma("unroll")                                                      \
        for (int g = 0; g < 4; ++g)                                            \
            RA[(U) * 4 + g] = *reinterpret_cast<const floatx4*>(               \
                abase + (size_t)((U) * 4 + g) * NN + (size_t)(TT) * APH);      \
        asm volatile("" ::: "memory");                                         \
    }

#define ISSUE_B(RB, BP)                                                       \
    {                                                                         \
        _Pragma("unroll")                                                     \
        for (int s = 0; s < 2; ++s)                                           \
            _Pragma("unroll")                                                 \
            for (int f = 0; f < 4; ++f)                                       \
                RB[s * 4 + f] =                                               \
                    *reinterpret_cast<const short8*>(BP + s * 2048 + f * 512);\
        BP += 8192;                                                           \
        asm volatile("" ::: "memory");                                        \
    }

#define STASH(RA, C)                                                         \
    {                                                                        \
        _Pragma("unroll")                                                    \
        for (int g = 0; g < 16; ++g) {                                       \
            short4v w_;                                                      \
            w_.x = bf16b(RA[g].x); w_.y = bf16b(RA[g].y);                    \
            w_.z = bf16b(RA[g].z); w_.w = bf16b(RA[g].w);                    \
            *reinterpret_cast<short4v*>((C) + sbyte + g * 80) = w_;          \
        }                                                                    \
    }

    floatx4 acc0 = {0.f, 0.f, 0.f, 0.f};
    floatx4 acc1 = {0.f, 0.f, 0.f, 0.f};
    floatx4 acc2 = {0.f, 0.f, 0.f, 0.f};
    floatx4 acc3 = {0.f, 0.f, 0.f, 0.f};

#define COMPUTE(C, RB, U)                                                         \
    {                                                                             \
        _Pragma("unroll")                                                         \
        for (int s = 0; s < 2; ++s) {                                             \
            short8 af = *reinterpret_cast<const short8*>(                         \
                (C) + aoff + (U) * 2560 + s * 1280);                              \
            acc0 = __builtin_amdgcn_mfma_f32_16x16x32_bf16(af, RB[s*4+0], acc0, 0, 0, 0); \
            acc1 = __builtin_amdgcn_mfma_f32_16x16x32_bf16(af, RB[s*4+1], acc1, 0, 0, 0); \
            acc2 = __builtin_amdgcn_mfma_f32_16x16x32_bf16(af, RB[s*4+2], acc2, 0, 0, 0); \
            acc3 = __builtin_amdgcn_mfma_f32_16x16x32_bf16(af, RB[s*4+3], acc3, 0, 0, 0); \
        }                                                                         \
    }

    // prologue: A(0) full -> Sa; B(0),B(1); A(1) full -> Sb; stash A(0)
    ISSUE_A4(Sa, 0, 0); ISSUE_A4(Sa, 0, 1); ISSUE_A4(Sa, 0, 2); ISSUE_A4(Sa, 0, 3);
    ISSUE_B(Ba, bpA); ISSUE_B(Bb, bpB);
    ISSUE_A4(Sb, 1, 0); ISSUE_A4(Sb, 1, 1); ISSUE_A4(Sb, 1, 2); ISSUE_A4(Sb, 1, 3);
    STASH(Sa, c0);   // waits Sa (oldest); Sb + B stay outstanding

    for (int T = 0; T < NAPH; T += 2) {
        // phase T (even): compute c0; issue A(T+2) groups into Sa; stash A(T+1)
        COMPUTE(c0, Ba, 0); if (T + 2 < NAPH) ISSUE_A4(Sa, T + 2, 0); if (4*T + 2 < 256) ISSUE_B(Ba, bpA);
        COMPUTE(c0, Bb, 1); if (T + 2 < NAPH) ISSUE_A4(Sa, T + 2, 1); if (4*T + 3 < 256) ISSUE_B(Bb, bpB);
        COMPUTE(c0, Ba, 2); if (T + 2 < NAPH) ISSUE_A4(Sa, T + 2, 2); if (4*T + 4 < 256) ISSUE_B(Ba, bpA);
        COMPUTE(c0, Bb, 3); if (T + 2 < NAPH) ISSUE_A4(Sa, T + 2, 3); if (4*T + 5 < 256) ISSUE_B(Bb, bpB);
        if (T + 1 < NAPH) STASH(Sb, c1);   // A(T+1); A(T+2)+B newer, stay out

        // phase T+1 (odd): compute c1; issue A(T+3) into Sb; stash A(T+2)
        COMPUTE(c1, Ba, 0); if (T + 3 < NAPH) ISSUE_A4(Sb, T + 3, 0); if (4*T + 6 < 256) ISSUE_B(Ba, bpA);
        COMPUTE(c1, Bb, 1); if (T + 3 < NAPH) ISSUE_A4(Sb, T + 3, 1); if (4*T + 7 < 256) ISSUE_B(Bb, bpB);
        COMPUTE(c1, Ba, 2); if (T + 3 < NAPH) ISSUE_A4(Sb, T + 3, 2); if (4*T + 8 < 256) ISSUE_B(Ba, bpA);
        COMPUTE(c1, Bb, 3); if (T + 3 < NAPH) ISSUE_A4(Sb, T + 3, 3); if (4*T + 9 < 256) ISSUE_B(Bb, bpB);
        if (T + 2 < NAPH) STASH(Sa, c0);   // A(T+2)
    }

    // C/D: col(N) = r, row(M) = kg*4 + j  (verified r1-r7)
    const int orow = row0 + kg * 4;
    float* op = out + (size_t)orow * DD + r;
#pragma unroll
    for (int j = 0; j < 4; ++j) {
        op[(size_t)j * DD + 0]  = acc0[j];
        op[(size_t)j * DD + 16] = acc1[j];
        op[(size_t)j * DD + 32] = acc2[j];
        op[(size_t)j * DD + 48] = acc3[j];
    }
}

extern "C" void kernel_launch(void* const* d_in, const int* in_sizes, int n_in,
                              void* d_out, int out_size, void* d_ws, size_t ws_size,
                              hipStream_t stream) {
    const float* x   = (const float*)d_in[0];
    const float* adj = (const float*)d_in[1];
    const float* u   = (const float*)d_in[2];
    float* out = (float*)d_out;
    short* bfrag = (short*)d_ws;   // 16384*64 bf16 = 2 MB

    prep_kernel<<<dim3(512), dim3(256), 0, stream>>>(x, u, bfrag);
    gemm_kernel<<<dim3(NN / MT), dim3(64), 0, stream>>>(adj, bfrag, out);
}

// Round 10
// 205.849 us; speedup vs baseline: 1.1499x; 1.0243x over previous
//
#include <hip/hip_runtime.h>
#include <hip/hip_bf16.h>

// LightGCN layer: out = adj @ (x * (u >= 0.1) / 0.9)
// x: [16384,64] f32, adj: [16384,16384] f32, u: [16384,64] f32, out: [16384,64] f32
//
// Round 10: RESUBMIT of r9 (container died before benching — no data).
// r8 (best, 210.8us) + ONE change: non-temporal A (adj) loads.
// adj is a zero-reuse 1.07GB stream; caching it in L2 evicts the shared 2MB
// B buffer, forcing straggler waves to re-fetch B from HBM (~0.15-0.2GB leak
// inferred from the BW deficit). nt stops the pollution. Everything else is
// byte-identical to r8 (1KB-contiguous A instrs, barrier-free 1-wave blocks,
// counted-vmcnt ordering, B-in-regs as MFMA fragments).

#define NN 16384
#define DD 64
#define MT 16
#define APH 256                // A-phase: K floats per staged chunk
#define NAPH (NN / APH)        // 64 A-phases
#define CHUNK 10240            // 4 sub-chunks x 2560 B

typedef __attribute__((ext_vector_type(4))) float floatx4;
typedef __attribute__((ext_vector_type(4))) short short4v;
typedef __attribute__((ext_vector_type(8))) short short8;

static __device__ __forceinline__ short bf16b(float f) {
    union { __hip_bfloat16 h; short s; } cv;
    cv.h = __float2bfloat16(f);
    return cv.s;
}

// B in MFMA fragment-linear order (unchanged, verified r1-r8):
// chunk c = s*256 + f*64 + lane; shorts at c*8:
// element j = B[s*32 + (lane>>4)*8 + j][f*16 + (lane&15)]
__global__ void __launch_bounds__(256) prep_kernel(const float* __restrict__ x,
                                                   const float* __restrict__ u,
                                                   short* __restrict__ bfrag) {
    int c = blockIdx.x * 256 + threadIdx.x;
    int lane = c & 63;
    int f = (c >> 6) & 3;
    int s = c >> 8;
    int col = f * 16 + (lane & 15);
    int k0 = s * 32 + (lane >> 4) * 8;
    short8 v;
#pragma unroll
    for (int j = 0; j < 8; ++j) {
        int idx = (k0 + j) * DD + col;
        float xv = x[idx];
        float uv = u[idx];
        float xd = (uv >= 0.1f) ? xv * (1.0f / 0.9f) : 0.0f;
        v[j] = bf16b(xd);
    }
    *reinterpret_cast<short8*>(bfrag + (size_t)c * 8) = v;
}

__global__ void __launch_bounds__(64) gemm_kernel(const float* __restrict__ adj,
                                                  const short* __restrict__ bfrag,
                                                  float* __restrict__ out) {
    __shared__ char smem[2 * CHUNK];   // 20480 B, wave-private (1 wave/block)
    char* c0 = smem;
    char* c1 = smem + CHUNK;

    const int lane = threadIdx.x & 63;
    const int r    = lane & 15;        // MFMA A-row / output col
    const int kg   = lane >> 4;        // MFMA k-group
    const int row0 = blockIdx.x * MT;

    // A-load: instr g loads row g's [T*256 + lane*4 .. +3] -> 1KB contiguous/instr
    const float* abase = adj + (size_t)row0 * NN + (size_t)lane * 4;
    // STASH: lane's 4 floats are k0 = lane*4 of row g. Decompose k0:
    //   u=lane>>4 (sub-chunk), s=(lane&15)>>3, kg'=(lane&7)>>1, half=lane&1
    const int sbyte = (lane >> 4) * 2560 + ((lane & 15) >> 3) * 1280 +
                      ((lane & 7) >> 1) * 16 + (lane & 1) * 8;
    const int aoff  = r * 80 + kg * 16;   // A-frag read (+ u*2560 + s*1280)

    const short* bpA = bfrag + (size_t)lane * 8;   // even sub-phases
    const short* bpB = bpA + 4096;                 // odd sub-phases

    floatx4 Sa[16], Sb[16];
    short8  Ba[8], Bb[8];

#define ISSUE_A4(RA, TT, U)                                                    \
    {                                                                          \
        _Pragma("unroll")                                                      \
        for (int g = 0; g < 4; ++g)                                            \
            RA[(U) * 4 + g] = __builtin_nontemporal_load(                      \
                reinterpret_cast<const floatx4*>(                              \
                    abase + (size_t)((U) * 4 + g) * NN + (size_t)(TT) * APH)); \
        asm volatile("" ::: "memory");                                         \
    }

#define ISSUE_B(RB, BP)                                                       \
    {                                                                         \
        _Pragma("unroll")                                                     \
        for (int s = 0; s < 2; ++s)                                           \
            _Pragma("unroll")                                                 \
            for (int f = 0; f < 4; ++f)                                       \
                RB[s * 4 + f] =                                               \
                    *reinterpret_cast<const short8*>(BP + s * 2048 + f * 512);\
        BP += 8192;                                                           \
        asm volatile("" ::: "memory");                                        \
    }

#define STASH(RA, C)                                                         \
    {                                                                        \
        _Pragma("unroll")                                                    \
        for (int g = 0; g < 16; ++g) {                                       \
            short4v w_;                                                      \
            w_.x = bf16b(RA[g].x); w_.y = bf16b(RA[g].y);                    \
            w_.z = bf16b(RA[g].z); w_.w = bf16b(RA[g].w);                    \
            *reinterpret_cast<short4v*>((C) + sbyte + g * 80) = w_;          \
        }                                                                    \
    }

    floatx4 acc0 = {0.f, 0.f, 0.f, 0.f};
    floatx4 acc1 = {0.f, 0.f, 0.f, 0.f};
    floatx4 acc2 = {0.f, 0.f, 0.f, 0.f};
    floatx4 acc3 = {0.f, 0.f, 0.f, 0.f};

#define COMPUTE(C, RB, U)                                                         \
    {                                                                             \
        _Pragma("unroll")                                                         \
        for (int s = 0; s < 2; ++s) {                                             \
            short8 af = *reinterpret_cast<const short8*>(                         \
                (C) + aoff + (U) * 2560 + s * 1280);                              \
            acc0 = __builtin_amdgcn_mfma_f32_16x16x32_bf16(af, RB[s*4+0], acc0, 0, 0, 0); \
            acc1 = __builtin_amdgcn_mfma_f32_16x16x32_bf16(af, RB[s*4+1], acc1, 0, 0, 0); \
            acc2 = __builtin_amdgcn_mfma_f32_16x16x32_bf16(af, RB[s*4+2], acc2, 0, 0, 0); \
            acc3 = __builtin_amdgcn_mfma_f32_16x16x32_bf16(af, RB[s*4+3], acc3, 0, 0, 0); \
        }                                                                         \
    }

    // prologue: A(0) full -> Sa; B(0),B(1); A(1) full -> Sb; stash A(0)
    ISSUE_A4(Sa, 0, 0); ISSUE_A4(Sa, 0, 1); ISSUE_A4(Sa, 0, 2); ISSUE_A4(Sa, 0, 3);
    ISSUE_B(Ba, bpA); ISSUE_B(Bb, bpB);
    ISSUE_A4(Sb, 1, 0); ISSUE_A4(Sb, 1, 1); ISSUE_A4(Sb, 1, 2); ISSUE_A4(Sb, 1, 3);
    STASH(Sa, c0);   // waits Sa (oldest); Sb + B stay outstanding

    for (int T = 0; T < NAPH; T += 2) {
        // phase T (even): compute c0; issue A(T+2) groups into Sa; stash A(T+1)
        COMPUTE(c0, Ba, 0); if (T + 2 < NAPH) ISSUE_A4(Sa, T + 2, 0); if (4*T + 2 < 256) ISSUE_B(Ba, bpA);
        COMPUTE(c0, Bb, 1); if (T + 2 < NAPH) ISSUE_A4(Sa, T + 2, 1); if (4*T + 3 < 256) ISSUE_B(Bb, bpB);
        COMPUTE(c0, Ba, 2); if (T + 2 < NAPH) ISSUE_A4(Sa, T + 2, 2); if (4*T + 4 < 256) ISSUE_B(Ba, bpA);
        COMPUTE(c0, Bb, 3); if (T + 2 < NAPH) ISSUE_A4(Sa, T + 2, 3); if (4*T + 5 < 256) ISSUE_B(Bb, bpB);
        if (T + 1 < NAPH) STASH(Sb, c1);   // A(T+1); A(T+2)+B newer, stay out

        // phase T+1 (odd): compute c1; issue A(T+3) into Sb; stash A(T+2)
        COMPUTE(c1, Ba, 0); if (T + 3 < NAPH) ISSUE_A4(Sb, T + 3, 0); if (4*T + 6 < 256) ISSUE_B(Ba, bpA);
        COMPUTE(c1, Bb, 1); if (T + 3 < NAPH) ISSUE_A4(Sb, T + 3, 1); if (4*T + 7 < 256) ISSUE_B(Bb, bpB);
        COMPUTE(c1, Ba, 2); if (T + 3 < NAPH) ISSUE_A4(Sb, T + 3, 2); if (4*T + 8 < 256) ISSUE_B(Ba, bpA);
        COMPUTE(c1, Bb, 3); if (T + 3 < NAPH) ISSUE_A4(Sb, T + 3, 3); if (4*T + 9 < 256) ISSUE_B(Bb, bpB);
        if (T + 2 < NAPH) STASH(Sa, c0);   // A(T+2)
    }

    // C/D: col(N) = r, row(M) = kg*4 + j  (verified r1-r8)
    const int orow = row0 + kg * 4;
    float* op = out + (size_t)orow * DD + r;
#pragma unroll
    for (int j = 0; j < 4; ++j) {
        op[(size_t)j * DD + 0]  = acc0[j];
        op[(size_t)j * DD + 16] = acc1[j];
        op[(size_t)j * DD + 32] = acc2[j];
        op[(size_t)j * DD + 48] = acc3[j];
    }
}

extern "C" void kernel_launch(void* const* d_in, const int* in_sizes, int n_in,
                              void* d_out, int out_size, void* d_ws, size_t ws_size,
                              hipStream_t stream) {
    const float* x   = (const float*)d_in[0];
    const float* adj = (const float*)d_in[1];
    const float* u   = (const float*)d_in[2];
    float* out = (float*)d_out;
    short* bfrag = (short*)d_ws;   // 16384*64 bf16 = 2 MB

    prep_kernel<<<dim3(512), dim3(256), 0, stream>>>(x, u, bfrag);
    gemm_kernel<<<dim3(NN / MT), dim3(64), 0, stream>>>(adj, bfrag, out);
}